// Round 4
// baseline (1014.874 us; speedup 1.0000x reference)
//
#include <hip/hip_runtime.h>
#include <stdint.h>

#define T_TOK 8192
#define H_DIM 2048
#define F_DIM 1408
#define E_NUM 8
#define GU_DIM 2816   /* 2F */
#define NSLOT 16384   /* T * top_k */

typedef short bf16x8 __attribute__((ext_vector_type(8)));
typedef float f32x4 __attribute__((ext_vector_type(4)));

__device__ __forceinline__ unsigned short f2bf(float f) {
  union { float f; unsigned u; } v; v.f = f;
  unsigned r = v.u + 0x7fffu + ((v.u >> 16) & 1u);
  return (unsigned short)(r >> 16);
}
__device__ __forceinline__ float bf2f(unsigned short h) {
  union { unsigned u; float f; } v; v.u = ((unsigned)h) << 16;
  return v.f;
}

__device__ __forceinline__ void gload16(const unsigned short* g, unsigned short* l) {
  __builtin_amdgcn_global_load_lds(
      (const __attribute__((address_space(1))) unsigned int*)g,
      (__attribute__((address_space(3))) unsigned int*)l, 16, 0, 0);
}

/* ---------------- cast fp32 -> bf16, vectorized x4 ---------------- */
__global__ void cast_kernel(const float* __restrict__ in,
                            unsigned short* __restrict__ out, long n4) {
  long i = (long)blockIdx.x * blockDim.x + threadIdx.x;
  long stride = (long)gridDim.x * blockDim.x;
  for (; i < n4; i += stride) {
    float4 f = ((const float4*)in)[i];
    ushort4 o;
    o.x = f2bf(f.x); o.y = f2bf(f.y); o.z = f2bf(f.z); o.w = f2bf(f.w);
    ((ushort4*)out)[i] = o;
  }
}

/* cast w1 with gate/up row interleave (see round-0 notes) */
__global__ void cast_w1_kernel(const float* __restrict__ w1,
                               unsigned short* __restrict__ W1bf) {
  const long n4tot = (long)E_NUM * GU_DIM * (H_DIM / 4);
  long i = (long)blockIdx.x * blockDim.x + threadIdx.x;
  long stride = (long)gridDim.x * blockDim.x;
  for (; i < n4tot; i += stride) {
    int h4 = (int)(i & (H_DIM / 4 - 1));
    long rn = i >> 9;
    int n = (int)(rn % GU_DIM);
    int e = (int)(rn / GU_DIM);
    int group = n >> 5, within = n & 31;
    int f = group * 16 + (within & 15);
    int src = (within < 16) ? f : (F_DIM + f);
    float4 v = ((const float4*)w1)[((long)e * GU_DIM + src) * (H_DIM / 4) + h4];
    ushort4 o;
    o.x = f2bf(v.x); o.y = f2bf(v.y); o.z = f2bf(v.z); o.w = f2bf(v.w);
    ((ushort4*)W1bf)[i] = o;
  }
}

/* ---------------- router: softmax top-2 + counts ---------------- */
__global__ void router_kernel(const float* __restrict__ logits,
                              int* __restrict__ counts,
                              int* __restrict__ tok_e, float* __restrict__ tok_w) {
  int t = blockIdx.x * blockDim.x + threadIdx.x;
  if (t >= T_TOK) return;
  float l[E_NUM];
  float4 a = ((const float4*)logits)[(size_t)t * 2];
  float4 b = ((const float4*)logits)[(size_t)t * 2 + 1];
  l[0]=a.x; l[1]=a.y; l[2]=a.z; l[3]=a.w;
  l[4]=b.x; l[5]=b.y; l[6]=b.z; l[7]=b.w;
  int i0 = 0; float m0v = l[0];
  #pragma unroll
  for (int e = 1; e < E_NUM; ++e) if (l[e] > m0v) { m0v = l[e]; i0 = e; }
  int i1 = -1; float m1v = -3.0e38f;
  #pragma unroll
  for (int e = 0; e < E_NUM; ++e) if (e != i0 && l[e] > m1v) { m1v = l[e]; i1 = e; }
  float e1 = __expf(m1v - m0v);
  float inv = 1.0f / (1.0f + e1);
  tok_e[2*t]   = i0; tok_w[2*t]   = inv;
  tok_e[2*t+1] = i1; tok_w[2*t+1] = e1 * inv;
  atomicAdd(&counts[i0], 1);
  atomicAdd(&counts[i1], 1);
}

__global__ void scan_kernel(const int* __restrict__ counts,
                            int* __restrict__ offsets, int* __restrict__ cursors) {
  if (threadIdx.x == 0 && blockIdx.x == 0) {
    int o = 0;
    for (int e = 0; e < E_NUM; ++e) { offsets[e] = o; cursors[e] = o; o += counts[e]; }
  }
}

__global__ void scatter_kernel(const int* __restrict__ tok_e, const float* __restrict__ tok_w,
                               int* __restrict__ cursors,
                               int* __restrict__ token_ids, float* __restrict__ slot_w,
                               int* __restrict__ slot_of) {
  int t = blockIdx.x * blockDim.x + threadIdx.x;
  if (t >= T_TOK) return;
  #pragma unroll
  for (int j = 0; j < 2; ++j) {
    int e = tok_e[2*t+j];
    int slot = atomicAdd(&cursors[e], 1);
    token_ids[slot] = t;
    slot_w[slot] = tok_w[2*t+j];
    slot_of[2*t+j] = slot;
  }
}

/* ---------------- 256x256 pipelined bf16 MFMA GEMM, C = A * B^T ----------------
 * BM=BN=256, BK=64, 512 threads (8 waves 2Mx4N), 16x16x32 mfma, LDS 128 KiB.
 * Phases per K-tile: P1=Q00(af0,bf0) P2=Q01(af0,bf1) P3=Q11(af1,bf1) P4=Q10(af1,bf0).
 * bf0 held P1->P4, bf1 held P2->P3 (each B half ds_read ONCE per K-tile).
 * READ-AHEAD: af1=A1(u) at P2-top (consumed P3/P4), af0'=A0(u+1) at P4-top
 * (consumed next P1/P2); counted lgkmcnt leaves read-ahead in flight.
 * STAGES: P1: A1(u+1)+B0(u+1); P2: B1(u+1); P3: A0(u+2). No phase stages a region
 * it reads; every restage-issue is >=1 barrier after all waves' read-drain.
 * VM waits (each >=1 barrier before first cross-wave read of the region):
 *   steady: vmcnt(2)@P1-top [B1(u)], vmcnt(6)@P3-top [A0(u+1)],
 *           vmcnt(4)@P4-end [A1(u+1),B0(u+1)].
 *   TAIL (u==NT-1): P1-top uses vmcnt(0) — staging guards reorder the in-flight
 *   queue, so B1(NT-1) is no longer drained by vmcnt(2) (this was the round-2
 *   race). Full drain once per block is negligible.
 * XCD swizzle (m204 bijective) with B-panel-major decode.
 */
#define BARRIER() __builtin_amdgcn_s_barrier()
#define SCHED0()  __builtin_amdgcn_sched_barrier(0)
#define LGKM0()  do { asm volatile("s_waitcnt lgkmcnt(0)" ::: "memory"); SCHED0(); } while (0)
#define LGKM8()  do { asm volatile("s_waitcnt lgkmcnt(8)" ::: "memory"); SCHED0(); } while (0)
#define VM0()    asm volatile("s_waitcnt vmcnt(0)" ::: "memory")
#define VM2()    asm volatile("s_waitcnt vmcnt(2)" ::: "memory")
#define VM4()    asm volatile("s_waitcnt vmcnt(4)" ::: "memory")
#define VM6()    asm volatile("s_waitcnt vmcnt(6)" ::: "memory")

#define STAGE_A(BASE, P0, P1v, KOFF) do { \
    gload16((P0) + (KOFF), &lds[(BASE) + (w << 9)]); \
    gload16((P1v) + (KOFF), &lds[(BASE) + 4096 + (w << 9)]); \
  } while (0)
#define STAGE_B(BASE, Ph, KOFF) do { \
    gload16((Ph) + (KOFF), &lds[(BASE) + (w << 9)]); \
    gload16((Ph) + (size_t)64 * K + (KOFF), &lds[(BASE) + 4096 + (w << 9)]); \
  } while (0)

#define LOADA(AF, BASE) do { \
    _Pragma("unroll") \
    for (int tm_ = 0; tm_ < 4; ++tm_) { \
      AF[tm_][0] = *(const bf16x8*)&lds[(BASE) + aoff[tm_] + koff0]; \
      AF[tm_][1] = *(const bf16x8*)&lds[(BASE) + aoff[tm_] + koff1]; \
    } \
  } while (0)

#define LOADB(BF, BASE) do { \
    _Pragma("unroll") \
    for (int tn_ = 0; tn_ < 2; ++tn_) { \
      BF[tn_][0] = *(const bf16x8*)&lds[(BASE) + boff[tn_] + koff0]; \
      BF[tn_][1] = *(const bf16x8*)&lds[(BASE) + boff[tn_] + koff1]; \
    } \
  } while (0)

#define MMAQ(Q, AF, BF) do { \
    _Pragma("unroll") \
    for (int tm_ = 0; tm_ < 4; ++tm_) { \
      _Pragma("unroll") \
      for (int tn_ = 0; tn_ < 2; ++tn_) { \
        acc[Q][tm_][tn_] = __builtin_amdgcn_mfma_f32_16x16x32_bf16( \
            AF[tm_][0], BF[tn_][0], acc[Q][tm_][tn_], 0, 0, 0); \
        acc[Q][tm_][tn_] = __builtin_amdgcn_mfma_f32_16x16x32_bf16( \
            AF[tm_][1], BF[tn_][1], acc[Q][tm_][tn_], 0, 0, 0); \
      } \
    } \
  } while (0)

template <int K, bool GATHER, int EPI>
__global__ __launch_bounds__(512, 2)
void gemm256_kernel(const unsigned short* __restrict__ A,
                    const unsigned short* __restrict__ B,
                    const int* __restrict__ counts, const int* __restrict__ offsets,
                    const int* __restrict__ token_ids, const float* __restrict__ slot_w,
                    unsigned short* __restrict__ OutB, long bstride_e) {
  constexpr int NT = K / 64;
  const int e = blockIdx.z;
  const int count = counts[e];

  /* XCD-aware bijective swizzle; decode B-panel-major (consecutive wg share lx) */
  const int NXg = gridDim.x;                 /* N-blocks */
  int f = blockIdx.y * NXg + blockIdx.x;
  int nwg = NXg * 32;                        /* gridDim.y == T_TOK/256 == 32 */
  int qq = nwg >> 3, rr = nwg & 7;
  int xcd = f & 7, loc = f >> 3;
  int wg = (xcd < rr ? xcd * (qq + 1) : rr * (qq + 1) + (xcd - rr) * qq) + loc;
  const int m0 = (wg & 31) * 256;
  const int n0 = (wg >> 5) * 256;

  if (m0 >= count) return;
  const int off = offsets[e];
  const unsigned short* Bexp = B + (size_t)e * bstride_e;

  /* A: [0,32768) shorts, B: [32768,65536). region(buf,half) = 8192 shorts. */
  __shared__ __align__(16) unsigned short lds[65536];

  const int t = threadIdx.x;
  const int w = t >> 6, lane = t & 63;
  const int wm = w >> 2, wn = w & 3;
  const int quad = lane >> 4, col = lane & 15;
  const int sw = col & 7;

  /* staging pointers: row = half*128 + sweep*64 + t/8, pre-swizzled chunk */
  const int colb = (((t & 7) ^ ((t >> 3) & 7)) * 8);
  const unsigned short* pa[2][2];
  const unsigned short* pb[2];
  #pragma unroll
  for (int h = 0; h < 2; ++h) {
    #pragma unroll
    for (int s = 0; s < 2; ++s) {
      int r = h * 128 + s * 64 + (t >> 3);
      int mr = m0 + r;
      if (GATHER) {
        int tok = (mr < count) ? token_ids[off + mr] : 0;
        pa[h][s] = A + (size_t)tok * K + colb;
      } else {
        int row = (mr < count) ? (off + mr) : 0;
        pa[h][s] = A + (size_t)row * K + colb;
      }
    }
    pb[h] = Bexp + (size_t)(n0 + h * 128 + (t >> 3)) * K + colb;
  }

  int aoff[4], boff[2];
  #pragma unroll
  for (int tm = 0; tm < 4; ++tm) aoff[tm] = (wm * 64 + tm * 16 + col) * 64;
  #pragma unroll
  for (int tn = 0; tn < 2; ++tn) boff[tn] = (wn * 32 + tn * 16 + col) * 64;
  const int koff0 = ((0 * 4 + quad) ^ sw) * 8;
  const int koff1 = ((1 * 4 + quad) ^ sw) * 8;

  const f32x4 zero = {0.f, 0.f, 0.f, 0.f};
  f32x4 acc[4][4][2];
  #pragma unroll
  for (int q = 0; q < 4; ++q)
    #pragma unroll
    for (int tm = 0; tm < 4; ++tm)
      #pragma unroll
      for (int tn = 0; tn < 2; ++tn) acc[q][tm][tn] = zero;

  bf16x8 af0[4][2], af1[4][2], bf0[2][2], bf1[2][2];

  /* -------- prologue: A0(0),B0(0),A1(0),B1(0),A0(1); pre-read af0=A0(0) */
  STAGE_A(0,             pa[0][0], pa[0][1], 0);
  STAGE_B(32768,         pb[0], 0);
  STAGE_A(8192,          pa[1][0], pa[1][1], 0);
  STAGE_B(32768 + 8192,  pb[1], 0);
  STAGE_A(16384,         pa[0][0], pa[0][1], 64);
  VM6();            /* A0(0),B0(0) landed (leaves A1(0),B1(0),A0(1)) */
  BARRIER();
  LOADA(af0, 0);

  for (int u = 0; u < NT; ++u) {
    const int b = u & 1, nb = b ^ 1;
    const int bA0 = b * 16384,  bA1 = bA0 + 8192;
    const int nbA0 = nb * 16384, nbA1 = nbA0 + 8192;
    const int bB0 = 32768 + bA0, bB1 = 32768 + bA1;
    const int nbB0 = 32768 + nbA0, nbB1 = 32768 + nbA1;
    const int k1 = (u + 1) * 64, k2 = (u + 2) * 64;

    /* ---- P1: Q00 = af0 x bf0; stage A1(u+1)+B0(u+1) ---- */
    if (u + 1 < NT) { VM2(); } else { VM0(); }  /* steady: B1(u) landed; tail: drain all */
    LOADB(bf0, bB0);
    if (u + 1 < NT) {
      STAGE_A(nbA1, pa[1][0], pa[1][1], k1);
      STAGE_B(nbB0, pb[0], k1);
    }
    SCHED0();
    BARRIER();
    LGKM0();                             /* af0 (read-ahead) + bf0 done */
    __builtin_amdgcn_s_setprio(1); MMAQ(0, af0, bf0); __builtin_amdgcn_s_setprio(0);
    BARRIER();

    /* ---- P2: Q01 = af0 x bf1; read-ahead af1=A1(u); stage B1(u+1) ---- */
    LOADB(bf1, bB1);
    SCHED0();                            /* pin B-reads before A-reads */
    LOADA(af1, bA1);
    if (u + 1 < NT) STAGE_B(nbB1, pb[1], k1);
    SCHED0();
    BARRIER();
    LGKM8();                             /* bf1 done; af1's 8 reads stay in flight */
    __builtin_amdgcn_s_setprio(1); MMAQ(1, af0, bf1); __builtin_amdgcn_s_setprio(0);
    BARRIER();

    /* ---- P3: Q11 = af1 x bf1 (held); stage A0(u+2) ---- */
    VM6();                               /* A0(u+1) in LDS (read next phase) */
    if (u + 2 < NT) STAGE_A(bA0, pa[0][0], pa[0][1], k2);
    SCHED0();
    BARRIER();
    LGKM0();                             /* af1 done */
    __builtin_amdgcn_s_setprio(1); MMAQ(3, af1, bf1); __builtin_amdgcn_s_setprio(0);
    BARRIER();

    /* ---- P4: Q10 = af1 x bf0 (held, no LDS read); read-ahead af0=A0(u+1) ---- */
    if (u + 1 < NT) LOADA(af0, nbA0);    /* stays in flight into next P1's LGKM0 */
    SCHED0();
    BARRIER();
    __builtin_amdgcn_s_setprio(1); MMAQ(2, af1, bf0); __builtin_amdgcn_s_setprio(0);
    VM4();                               /* A1(u+1),B0(u+1) landed before next P1 */
    BARRIER();
  }

  /* -------- epilogue. C/D: col=lane&15 (N), row=quad*4+reg (M). -------- */
  if (EPI == 0) {
    #pragma unroll
    for (int q = 0; q < 4; ++q) {
      const int qm = q >> 1, qn = q & 1;
      const int fb = (n0 >> 1) + qn * 64 + wn * 16 + col;
      #pragma unroll
      for (int tm = 0; tm < 4; ++tm)
        #pragma unroll
        for (int reg = 0; reg < 4; ++reg) {
          int m_l = qm * 128 + wm * 64 + tm * 16 + quad * 4 + reg;
          if (m0 + m_l < count) {
            float g = acc[q][tm][0][reg], uu = acc[q][tm][1][reg];
            OutB[(size_t)(off + m0 + m_l) * F_DIM + fb] =
                f2bf(g / (1.f + __expf(-g)) * uu);
          }
        }
    }
  } else {
    #pragma unroll
    for (int q = 0; q < 4; ++q) {
      const int qm = q >> 1, qn = q & 1;
      #pragma unroll
      for (int tm = 0; tm < 4; ++tm)
        #pragma unroll
        for (int reg = 0; reg < 4; ++reg) {
          int m_l = qm * 128 + wm * 64 + tm * 16 + quad * 4 + reg;
          if (m0 + m_l < count) {
            int slot = off + m0 + m_l;
            float wv = slot_w[slot];
            unsigned short* yrow = OutB + (size_t)slot * H_DIM + n0 + qn * 128 + wn * 32;
            yrow[col]      = f2bf(wv * acc[q][tm][0][reg]);
            yrow[16 + col] = f2bf(wv * acc[q][tm][1][reg]);
          }
        }
    }
  }
}

/* ---------------- out[t] = Y[s0(t)] + Y[s1(t)] ---------------- */
__global__ void combine_kernel(const unsigned short* __restrict__ Y,
                               const int* __restrict__ slot_of,
                               float* __restrict__ out) {
  const long n4 = (long)T_TOK * (H_DIM / 4);
  long i = (long)blockIdx.x * blockDim.x + threadIdx.x;
  long stride = (long)gridDim.x * blockDim.x;
  for (; i < n4; i += stride) {
    int h4 = (int)(i & (H_DIM / 4 - 1));
    int t = (int)(i >> 9);
    int s0 = slot_of[2 * t], s1 = slot_of[2 * t + 1];
    ushort4 a = ((const ushort4*)(Y + (size_t)s0 * H_DIM))[h4];
    ushort4 b = ((const ushort4*)(Y + (size_t)s1 * H_DIM))[h4];
    float4 o;
    o.x = bf2f(a.x) + bf2f(b.x);
    o.y = bf2f(a.y) + bf2f(b.y);
    o.z = bf2f(a.z) + bf2f(b.z);
    o.w = bf2f(a.w) + bf2f(b.w);
    ((float4*)out)[i] = o;
  }
}

extern "C" void kernel_launch(void* const* d_in, const int* in_sizes, int n_in,
                              void* d_out, int out_size, void* d_ws, size_t ws_size,
                              hipStream_t stream) {
  const float* hidden = (const float*)d_in[0];
  const float* rlog   = (const float*)d_in[1];
  const float* w1     = (const float*)d_in[2];
  const float* w2     = (const float*)d_in[3];
  float* out = (float*)d_out;
  char* ws = (char*)d_ws;

  size_t o = 0;
  auto take = [&](size_t bytes) { size_t r = o; o += (bytes + 255) & ~(size_t)255; return r; };
  unsigned short* Xbf  = (unsigned short*)(ws + take((size_t)T_TOK * H_DIM * 2));
  unsigned short* W1bf = (unsigned short*)(ws + take((size_t)E_NUM * GU_DIM * H_DIM * 2));
  unsigned short* W2bf = (unsigned short*)(ws + take((size_t)E_NUM * H_DIM * F_DIM * 2));
  unsigned short* Hb   = (unsigned short*)(ws + take((size_t)NSLOT * F_DIM * 2));
  unsigned short* Y    = (unsigned short*)(ws + take((size_t)NSLOT * H_DIM * 2));
  size_t ctrl_off = take(256 * 3);
  int* counts  = (int*)(ws + ctrl_off);
  int* offsets = (int*)(ws + ctrl_off + 256);
  int* cursors = (int*)(ws + ctrl_off + 512);
  int*   tok_e     = (int*)(ws + take((size_t)T_TOK * 2 * 4));
  float* tok_w     = (float*)(ws + take((size_t)T_TOK * 2 * 4));
  int*   token_ids = (int*)(ws + take((size_t)NSLOT * 4));
  float* slot_w    = (float*)(ws + take((size_t)NSLOT * 4));
  int*   slot_of   = (int*)(ws + take((size_t)NSLOT * 4));

  hipMemsetAsync(ws + ctrl_off, 0, 256 * 3, stream);

  cast_kernel<<<2048, 256, 0, stream>>>(hidden, Xbf, (long)T_TOK * H_DIM / 4);
  cast_w1_kernel<<<4096, 256, 0, stream>>>(w1, W1bf);
  cast_kernel<<<4096, 256, 0, stream>>>(w2, W2bf, (long)E_NUM * H_DIM * F_DIM / 4);

  router_kernel<<<T_TOK / 256, 256, 0, stream>>>(rlog, counts, tok_e, tok_w);
  scan_kernel<<<1, 64, 0, stream>>>(counts, offsets, cursors);
  scatter_kernel<<<T_TOK / 256, 256, 0, stream>>>(tok_e, tok_w, cursors,
                                                  token_ids, slot_w, slot_of);

  dim3 g1(GU_DIM / 256, T_TOK / 256, E_NUM);
  gemm256_kernel<H_DIM, true, 0><<<g1, 512, 0, stream>>>(
      Xbf, W1bf, counts, offsets, token_ids, slot_w, Hb,
      (long)GU_DIM * H_DIM);

  dim3 g2(H_DIM / 256, T_TOK / 256, E_NUM);
  gemm256_kernel<F_DIM, false, 1><<<g2, 512, 0, stream>>>(
      Hb, W2bf, counts, offsets, token_ids, slot_w, Y,
      (long)H_DIM * F_DIM);

  combine_kernel<<<4096, 256, 0, stream>>>(Y, slot_of, out);
}

// Round 5
// 854.090 us; speedup vs baseline: 1.1883x; 1.1883x over previous
//
#include <hip/hip_runtime.h>
#include <stdint.h>

#define T_TOK 8192
#define H_DIM 2048
#define F_DIM 1408
#define E_NUM 8
#define GU_DIM 2816   /* 2F */
#define NSLOT 16384   /* T * top_k */

typedef short bf16x8 __attribute__((ext_vector_type(8)));
typedef float f32x4 __attribute__((ext_vector_type(4)));

__device__ __forceinline__ unsigned short f2bf(float f) {
  union { float f; unsigned u; } v; v.f = f;
  unsigned r = v.u + 0x7fffu + ((v.u >> 16) & 1u);
  return (unsigned short)(r >> 16);
}
__device__ __forceinline__ float bf2f(unsigned short h) {
  union { unsigned u; float f; } v; v.u = ((unsigned)h) << 16;
  return v.f;
}

__device__ __forceinline__ void gload16(const unsigned short* g, unsigned short* l) {
  __builtin_amdgcn_global_load_lds(
      (const __attribute__((address_space(1))) unsigned int*)g,
      (__attribute__((address_space(3))) unsigned int*)l, 16, 0, 0);
}

/* ---------------- cast fp32 -> bf16, vectorized x4 ---------------- */
__global__ void cast_kernel(const float* __restrict__ in,
                            unsigned short* __restrict__ out, long n4) {
  long i = (long)blockIdx.x * blockDim.x + threadIdx.x;
  long stride = (long)gridDim.x * blockDim.x;
  for (; i < n4; i += stride) {
    float4 f = ((const float4*)in)[i];
    ushort4 o;
    o.x = f2bf(f.x); o.y = f2bf(f.y); o.z = f2bf(f.z); o.w = f2bf(f.w);
    ((ushort4*)out)[i] = o;
  }
}

/* cast w1 with gate/up row interleave:
 * dst row n (within expert): group=n>>5, within=n&31, f=group*16+(within&15)
 * src row = (within<16) ? f : F_DIM+f.
 * => GEMM1 columns n and n+16 (within each 32-group) are gate_f and up_f.
 * 32-bit index math throughout (n4tot < 2^24): the previous 64-bit %/ by
 * 2816 was a libcall-class sequence per float4. */
__global__ void cast_w1_kernel(const float* __restrict__ w1,
                               unsigned short* __restrict__ W1bf) {
  const int n4tot = E_NUM * GU_DIM * (H_DIM / 4);   /* 11,534,336 */
  int i = blockIdx.x * blockDim.x + threadIdx.x;
  int stride = gridDim.x * blockDim.x;
  for (; i < n4tot; i += stride) {
    int h4 = i & (H_DIM / 4 - 1);        /* 512 per row, pow2 */
    int rn = i >> 9;                     /* < 22528 */
    int e = rn / GU_DIM;                 /* const 32b div -> magic mul */
    int n = rn - e * GU_DIM;
    int group = n >> 5, within = n & 31;
    int f = group * 16 + (within & 15);
    int src = (within < 16) ? f : (F_DIM + f);
    float4 v = ((const float4*)w1)[((long)e * GU_DIM + src) * (H_DIM / 4) + h4];
    ushort4 o;
    o.x = f2bf(v.x); o.y = f2bf(v.y); o.z = f2bf(v.z); o.w = f2bf(v.w);
    ((ushort4*)W1bf)[i] = o;
  }
}

/* ---------------- router: softmax top-2 + counts ---------------- */
__global__ void router_kernel(const float* __restrict__ logits,
                              int* __restrict__ counts,
                              int* __restrict__ tok_e, float* __restrict__ tok_w) {
  int t = blockIdx.x * blockDim.x + threadIdx.x;
  if (t >= T_TOK) return;
  float l[E_NUM];
  float4 a = ((const float4*)logits)[(size_t)t * 2];
  float4 b = ((const float4*)logits)[(size_t)t * 2 + 1];
  l[0]=a.x; l[1]=a.y; l[2]=a.z; l[3]=a.w;
  l[4]=b.x; l[5]=b.y; l[6]=b.z; l[7]=b.w;
  int i0 = 0; float m0v = l[0];
  #pragma unroll
  for (int e = 1; e < E_NUM; ++e) if (l[e] > m0v) { m0v = l[e]; i0 = e; }
  int i1 = -1; float m1v = -3.0e38f;
  #pragma unroll
  for (int e = 0; e < E_NUM; ++e) if (e != i0 && l[e] > m1v) { m1v = l[e]; i1 = e; }
  float e1 = __expf(m1v - m0v);
  float inv = 1.0f / (1.0f + e1);
  tok_e[2*t]   = i0; tok_w[2*t]   = inv;
  tok_e[2*t+1] = i1; tok_w[2*t+1] = e1 * inv;
  atomicAdd(&counts[i0], 1);
  atomicAdd(&counts[i1], 1);
}

__global__ void scan_kernel(const int* __restrict__ counts,
                            int* __restrict__ offsets, int* __restrict__ cursors) {
  if (threadIdx.x == 0 && blockIdx.x == 0) {
    int o = 0;
    for (int e = 0; e < E_NUM; ++e) { offsets[e] = o; cursors[e] = o; o += counts[e]; }
  }
}

__global__ void scatter_kernel(const int* __restrict__ tok_e, const float* __restrict__ tok_w,
                               int* __restrict__ cursors,
                               int* __restrict__ token_ids, float* __restrict__ slot_w,
                               int* __restrict__ slot_of) {
  int t = blockIdx.x * blockDim.x + threadIdx.x;
  if (t >= T_TOK) return;
  #pragma unroll
  for (int j = 0; j < 2; ++j) {
    int e = tok_e[2*t+j];
    int slot = atomicAdd(&cursors[e], 1);
    token_ids[slot] = t;
    slot_w[slot] = tok_w[2*t+j];
    slot_of[2*t+j] = slot;
  }
}

/* ---------------- tiled bf16 MFMA GEMM, C = A * B^T ----------------
 * BM=BN=128, BK=64, 256 threads (4 waves, 2x2 of 64x64), 16x16x32 mfma.
 * LDS tile is XOR-swizzled in 16B chunks: slot (r, c) holds global chunk
 * (r, c ^ (r&7)) -> quad-group ds_read_b128 spreads over all 32 banks.
 * GATHER: A rows via token_ids (GEMM1) vs compact (GEMM2).
 * EPI 0: fused silu(gate)*up -> Hb bf16 (w1 rows pre-interleaved).
 * EPI 1: Y[slot] = slot_w * acc, bf16 store (combined later).
 *
 * XCD swizzle (T1, m204 bijective) over the ACTIVE block prefix only:
 * active blocks per expert-slice = yact*NX (yact = ceil(count/128)).
 * Swizzling the full grid would map all active blocks onto XCDs 0-1
 * (active f0 < 16*NX but chunks span the whole 64*NX grid). x-fastest
 * decode keeps each XCD chunk (~yact*NX/8 consecutive wg) walking all
 * x-blocks of a y-row together -> gathered A-tile + B-panels reuse in
 * that XCD's L2.
 */
template <int K, bool GATHER, int EPI, int NX>
__global__ __launch_bounds__(256, 2)
void gemm_kernel(const unsigned short* __restrict__ A,
                 const unsigned short* __restrict__ B,
                 const int* __restrict__ counts, const int* __restrict__ offsets,
                 const int* __restrict__ token_ids, const float* __restrict__ slot_w,
                 unsigned short* __restrict__ OutB, long bstride_e) {
  const int e = blockIdx.z;
  const int count = counts[e];

  const int yact = (count + 127) >> 7;        /* active y-blocks (<= gridDim.y) */
  const int nact = yact * NX;                 /* active blocks this z-slice */
  int f0 = blockIdx.y * NX + blockIdx.x;      /* HW-linear within slice (x fastest) */
  if (f0 >= nact) return;
  {
    int qq = nact >> 3, rr = nact & 7;
    int xcd = f0 & 7, loc = f0 >> 3;
    f0 = (xcd < rr ? xcd * (qq + 1) : rr * (qq + 1) + (xcd - rr) * qq) + loc;
  }
  const int m0 = (f0 / NX) * 128;             /* compile-time NX -> magic mul */
  const int n0 = (f0 % NX) * 128;

  const int off = offsets[e];
  const unsigned short* Bexp = B + (size_t)e * bstride_e;

  __shared__ __align__(16) unsigned short As[128 * 64];
  __shared__ __align__(16) unsigned short Bs[128 * 64];

  const int t = threadIdx.x;
  const int w = t >> 6, lane = t & 63;
  const int wm = w >> 1, wn = w & 1;
  const int quad = lane >> 4, col = lane & 15;

  // staging: lane covers row r = i*32 + t/8; its LDS chunk-col is t&7, so it
  // must fetch global chunk (t&7) ^ (r&7); r&7 == (t>>3)&7.
  const int colb = (((t & 7) ^ ((t >> 3) & 7)) * 8);
  const unsigned short* aptr[4];
  const unsigned short* bptr[4];
  #pragma unroll
  for (int i = 0; i < 4; ++i) {
    int r = i * 32 + (t >> 3);
    int mr = m0 + r;
    if (GATHER) {
      int tok = (mr < count) ? token_ids[off + mr] : 0;
      aptr[i] = A + (size_t)tok * K + colb;
    } else {
      int row = (mr < count) ? (off + mr) : 0;
      aptr[i] = A + (size_t)row * K + colb;
    }
    bptr[i] = Bexp + (size_t)(n0 + r) * K + colb;
  }

  const f32x4 zero = {0.f, 0.f, 0.f, 0.f};
  f32x4 acc[4][4];
  #pragma unroll
  for (int tm = 0; tm < 4; ++tm)
    #pragma unroll
    for (int tn = 0; tn < 4; ++tn) acc[tm][tn] = zero;

  const int sw = col & 7;  // (row & 7) for all fragment rows this lane reads

  for (int k0 = 0; k0 < K; k0 += 64) {
    #pragma unroll
    for (int i = 0; i < 4; ++i) {
      gload16(aptr[i] + k0, &As[i * 2048 + w * 512]);
      gload16(bptr[i] + k0, &Bs[i * 2048 + w * 512]);
    }
    __syncthreads();
    #pragma unroll
    for (int ks = 0; ks < 2; ++ks) {
      const int c = ks * 4 + quad;
      const int coff = (c ^ sw) * 8;
      bf16x8 af[4], bfr[4];
      #pragma unroll
      for (int tm = 0; tm < 4; ++tm)
        af[tm] = *(const bf16x8*)&As[(wm * 64 + tm * 16 + col) * 64 + coff];
      #pragma unroll
      for (int tn = 0; tn < 4; ++tn)
        bfr[tn] = *(const bf16x8*)&Bs[(wn * 64 + tn * 16 + col) * 64 + coff];
      #pragma unroll
      for (int tm = 0; tm < 4; ++tm)
        #pragma unroll
        for (int tn = 0; tn < 4; ++tn)
          acc[tm][tn] = __builtin_amdgcn_mfma_f32_16x16x32_bf16(af[tm], bfr[tn], acc[tm][tn], 0, 0, 0);
    }
    __syncthreads();
  }

  // C/D layout: col = lane&15, row = quad*4 + reg (m89-verified)
  if (EPI == 0) {
    // columns n and n+16 of each 32-group are gate_f / up_f, f = n/32*16 + col
    const int fbase = (n0 + wn * 64) >> 1;   // == (B/32)*16
    #pragma unroll
    for (int tm = 0; tm < 4; ++tm)
      #pragma unroll
      for (int reg = 0; reg < 4; ++reg) {
        int m_l = wm * 64 + tm * 16 + quad * 4 + reg;
        if (m0 + m_l < count) {
          unsigned short* hrow = OutB + (size_t)(off + m0 + m_l) * F_DIM + fbase + col;
          float g0 = acc[tm][0][reg], u0 = acc[tm][1][reg];
          float g1 = acc[tm][2][reg], u1 = acc[tm][3][reg];
          hrow[0]  = f2bf(g0 / (1.f + __expf(-g0)) * u0);
          hrow[16] = f2bf(g1 / (1.f + __expf(-g1)) * u1);
        }
      }
  } else {
    #pragma unroll
    for (int tm = 0; tm < 4; ++tm)
      #pragma unroll
      for (int reg = 0; reg < 4; ++reg) {
        int m_l = wm * 64 + tm * 16 + quad * 4 + reg;
        if (m0 + m_l < count) {
          int slot = off + m0 + m_l;
          float wv = slot_w[slot];
          unsigned short* yrow = OutB + (size_t)slot * H_DIM + n0 + wn * 64;
          #pragma unroll
          for (int tn = 0; tn < 4; ++tn)
            yrow[tn * 16 + col] = f2bf(wv * acc[tm][tn][reg]);
        }
      }
  }
}

/* ---------------- out[t] = Y[s0(t)] + Y[s1(t)] ---------------- */
__global__ void combine_kernel(const unsigned short* __restrict__ Y,
                               const int* __restrict__ slot_of,
                               float* __restrict__ out) {
  const long n4 = (long)T_TOK * (H_DIM / 4);
  long i = (long)blockIdx.x * blockDim.x + threadIdx.x;
  long stride = (long)gridDim.x * blockDim.x;
  for (; i < n4; i += stride) {
    int h4 = (int)(i & (H_DIM / 4 - 1));
    int t = (int)(i >> 9);
    int s0 = slot_of[2 * t], s1 = slot_of[2 * t + 1];
    ushort4 a = ((const ushort4*)(Y + (size_t)s0 * H_DIM))[h4];
    ushort4 b = ((const ushort4*)(Y + (size_t)s1 * H_DIM))[h4];
    float4 o;
    o.x = bf2f(a.x) + bf2f(b.x);
    o.y = bf2f(a.y) + bf2f(b.y);
    o.z = bf2f(a.z) + bf2f(b.z);
    o.w = bf2f(a.w) + bf2f(b.w);
    ((float4*)out)[i] = o;
  }
}

extern "C" void kernel_launch(void* const* d_in, const int* in_sizes, int n_in,
                              void* d_out, int out_size, void* d_ws, size_t ws_size,
                              hipStream_t stream) {
  const float* hidden = (const float*)d_in[0];
  const float* rlog   = (const float*)d_in[1];
  const float* w1     = (const float*)d_in[2];
  const float* w2     = (const float*)d_in[3];
  float* out = (float*)d_out;
  char* ws = (char*)d_ws;

  size_t o = 0;
  auto take = [&](size_t bytes) { size_t r = o; o += (bytes + 255) & ~(size_t)255; return r; };
  unsigned short* Xbf  = (unsigned short*)(ws + take((size_t)T_TOK * H_DIM * 2));
  unsigned short* W1bf = (unsigned short*)(ws + take((size_t)E_NUM * GU_DIM * H_DIM * 2));
  unsigned short* W2bf = (unsigned short*)(ws + take((size_t)E_NUM * H_DIM * F_DIM * 2));
  unsigned short* Hb   = (unsigned short*)(ws + take((size_t)NSLOT * F_DIM * 2));
  unsigned short* Y    = (unsigned short*)(ws + take((size_t)NSLOT * H_DIM * 2));
  size_t ctrl_off = take(256 * 3);           // counts / offsets / cursors
  int* counts  = (int*)(ws + ctrl_off);
  int* offsets = (int*)(ws + ctrl_off + 256);
  int* cursors = (int*)(ws + ctrl_off + 512);
  int*   tok_e     = (int*)(ws + take((size_t)T_TOK * 2 * 4));
  float* tok_w     = (float*)(ws + take((size_t)T_TOK * 2 * 4));
  int*   token_ids = (int*)(ws + take((size_t)NSLOT * 4));
  float* slot_w    = (float*)(ws + take((size_t)NSLOT * 4));
  int*   slot_of   = (int*)(ws + take((size_t)NSLOT * 4));

  hipMemsetAsync(ws + ctrl_off, 0, 256 * 3, stream);

  cast_kernel<<<2048, 256, 0, stream>>>(hidden, Xbf, (long)T_TOK * H_DIM / 4);
  cast_w1_kernel<<<4096, 256, 0, stream>>>(w1, W1bf);
  cast_kernel<<<4096, 256, 0, stream>>>(w2, W2bf, (long)E_NUM * H_DIM * F_DIM / 4);

  router_kernel<<<T_TOK / 256, 256, 0, stream>>>(rlog, counts, tok_e, tok_w);
  scan_kernel<<<1, 64, 0, stream>>>(counts, offsets, cursors);
  scatter_kernel<<<T_TOK / 256, 256, 0, stream>>>(tok_e, tok_w, cursors,
                                                  token_ids, slot_w, slot_of);

  dim3 g1(GU_DIM / 128, T_TOK / 128, E_NUM);
  gemm_kernel<H_DIM, true, 0, GU_DIM / 128><<<g1, 256, 0, stream>>>(
      Xbf, W1bf, counts, offsets, token_ids, slot_w, Hb,
      (long)GU_DIM * H_DIM);

  dim3 g2(H_DIM / 128, T_TOK / 128, E_NUM);
  gemm_kernel<F_DIM, false, 1, H_DIM / 128><<<g2, 256, 0, stream>>>(
      Hb, W2bf, counts, offsets, token_ids, slot_w, Y,
      (long)H_DIM * F_DIM);

  combine_kernel<<<4096, 256, 0, stream>>>(Y, slot_of, out);
}